// Round 1
// baseline (5540.239 us; speedup 1.0000x reference)
//
#include <hip/hip_runtime.h>
#include <hip/hip_bf16.h>

#define Bx 256
#define Tx 512
#define Ex 768
#define Hx 256
#define Gx 1024
#define Vx 7987
#define TCx 32
#define NCHx 16

typedef unsigned short u16;
typedef unsigned int u32;
typedef __bf16 bf16;
typedef bf16 bf16x8 __attribute__((ext_vector_type(8)));
typedef float f32x4 __attribute__((ext_vector_type(4)));

__device__ __forceinline__ u16 f2bf(float f) {
  union { float f; u32 u; } x; x.f = f;
  u32 r = x.u + 0x7fffu + ((x.u >> 16) & 1u);
  return (u16)(r >> 16);
}
__device__ __forceinline__ float bf2f(u16 b) {
  union { u32 u; float f; } x; x.u = ((u32)b) << 16;
  return x.f;
}
__device__ __forceinline__ void gload16(const void* g, void* l) {
  __builtin_amdgcn_global_load_lds((const __attribute__((address_space(1))) u32*)g,
                                   (__attribute__((address_space(3))) u32*)l, 16, 0, 0);
}
__device__ __forceinline__ float sigf(float x) { return 1.f / (1.f + __expf(-x)); }
__device__ __forceinline__ float tanhfast(float x) {
  x = fminf(fmaxf(x, -30.f), 30.f);
  float e = __expf(-2.f * x);
  return (1.f - e) / (1.f + e);
}

// ---------------- conversion / packing kernels ----------------

__global__ void k_cvt(const float* __restrict__ src, u16* __restrict__ dst, int n) {
  int i = blockIdx.x * blockDim.x + threadIdx.x;
  int st = gridDim.x * blockDim.x;
  for (; i < n; i += st) dst[i] = f2bf(src[i]);
}

__global__ void k_bias(const float* __restrict__ bihf, const float* __restrict__ bhhf,
                       const float* __restrict__ bihb, const float* __restrict__ bhhb,
                       float* __restrict__ bcat) {
  int i = blockIdx.x * blockDim.x + threadIdx.x;
  if (i < Gx) { bcat[i] = bihf[i] + bhhf[i]; bcat[Gx + i] = bihb[i] + bhhb[i]; }
}

// pack w_hh into fragment-linear layout:
// pk[((dir*8 + kc)*64 + nblk)*512 + lane*8 + j] = w[dir][n=nblk*16+(lane&15)][k=kc*32+(lane>>4)*8+j]
__global__ void k_pack_whh(const float* __restrict__ wf, const float* __restrict__ wb,
                           u16* __restrict__ pk) {
  int i = blockIdx.x * blockDim.x + threadIdx.x;
  int st = gridDim.x * blockDim.x;
  for (; i < 2 * 8 * 64 * 512; i += st) {
    int j = i & 7;
    int lane = (i >> 3) & 63;
    int nblk = (i >> 9) & 63;
    int kc = (i >> 15) & 7;
    int dir = i >> 18;
    int n = nblk * 16 + (lane & 15);
    int k = kc * 32 + ((lane >> 4) << 3) + j;
    const float* w = dir ? wb : wf;
    pk[i] = f2bf(w[n * Hx + k]);
  }
}

// ---------------- input projection GEMM (per time-chunk) ----------------
// xp[m*2048 + n], m = b*TCx + t (chunk-local t), n = dir*1024 + gate*256 + unit
__global__ __launch_bounds__(256) void k_xproj(
    const u16* __restrict__ embbf, const u16* __restrict__ wih,
    const int* __restrict__ input, const float* __restrict__ bcat,
    u16* __restrict__ xp, int t0) {
  __shared__ u16 sA[128 * 64];
  __shared__ u16 sB[128 * 64];
  const int tid = threadIdx.x;
  const int l = tid & 63, w = tid >> 6;
  const int bx = blockIdx.x & 15, by = blockIdx.x >> 4;
  const int wm = w >> 1, wn = w & 1;
  const int lr = l >> 3, lc = l & 7;

  f32x4 acc[4][4];
#pragma unroll
  for (int a = 0; a < 4; ++a)
#pragma unroll
    for (int b = 0; b < 4; ++b) acc[a][b] = f32x4{0.f, 0.f, 0.f, 0.f};

  // per-lane staging sources (constant across k loop, swizzled within 128B rows)
  size_t asrc[4], bsrc[4];
#pragma unroll
  for (int j = 0; j < 4; ++j) {
    int row = j * 32 + w * 8 + lr;
    int m = by * 128 + row;
    int eb = m >> 5, tt = m & 31;
    int er = input[eb * Tx + t0 + tt];
    asrc[j] = (size_t)er * (Ex * 2) + (size_t)((lc * 16) ^ ((row & 7) << 4));
    bsrc[j] = (size_t)(bx * 128 + row) * (Ex * 2) + (size_t)((lc * 16) ^ ((row & 7) << 4));
  }

  for (int kt = 0; kt < 12; ++kt) {
    const char* ebase = (const char*)embbf + (size_t)kt * 128;
    const char* wbase = (const char*)wih + (size_t)kt * 128;
#pragma unroll
    for (int j = 0; j < 4; ++j) {
      gload16(ebase + asrc[j], (char*)sA + (j * 32 + w * 8) * 128);
      gload16(wbase + bsrc[j], (char*)sB + (j * 32 + w * 8) * 128);
    }
    __syncthreads();
#pragma unroll
    for (int kk = 0; kk < 2; ++kk) {
      int kb = kk * 64 + ((l >> 4) * 16);
      bf16x8 av[4], bv[4];
#pragma unroll
      for (int f = 0; f < 4; ++f) {
        int r = wm * 64 + f * 16 + (l & 15);
        av[f] = *(const bf16x8*)((const char*)sA + r * 128 + (kb ^ ((r & 7) << 4)));
      }
#pragma unroll
      for (int f = 0; f < 4; ++f) {
        int n = wn * 64 + f * 16 + (l & 15);
        bv[f] = *(const bf16x8*)((const char*)sB + n * 128 + (kb ^ ((n & 7) << 4)));
      }
#pragma unroll
      for (int fm = 0; fm < 4; ++fm)
#pragma unroll
        for (int fn = 0; fn < 4; ++fn)
          acc[fm][fn] = __builtin_amdgcn_mfma_f32_16x16x32_bf16(av[fm], bv[fn], acc[fm][fn], 0, 0, 0);
    }
    __syncthreads();
  }
  // epilogue: add bias, store bf16
#pragma unroll
  for (int fn = 0; fn < 4; ++fn) {
    int col = bx * 128 + wn * 64 + fn * 16 + (l & 15);
    float bias = bcat[col];
#pragma unroll
    for (int fm = 0; fm < 4; ++fm) {
      int m0 = by * 128 + wm * 64 + fm * 16 + (l >> 4) * 4;
#pragma unroll
      for (int r = 0; r < 4; ++r)
        xp[(size_t)(m0 + r) * 2048 + col] = f2bf(acc[fm][fn][r] + bias);
    }
  }
}

// ---------------- recurrence (per time-chunk) ----------------
// 32 blocks = 2 dirs x 16 batch-slices (16 rows each), 8 waves.
// Wave w owns hidden units [w*32, w*32+32) for all 4 gates -> c,h update fully in-reg.
__global__ __launch_bounds__(512) void k_rnn(
    const u16* __restrict__ wpk_all, const u16* __restrict__ xp,
    const int* __restrict__ target, float* __restrict__ hst,
    float* __restrict__ cst, float* __restrict__ gath, int t0) {
  __shared__ u16 swb[2][32768];  // 2 x 64KB weight chunk (kc = 32 k-values, all 1024 n)
  __shared__ u16 sh[16 * 264];   // h bf16, padded row stride 264
  const int tid = threadIdx.x;
  const int l = tid & 63, w = tid >> 6;
  const int dir = blockIdx.x >> 4, slice = blockIdx.x & 15;
  const int b0 = slice * 16;
  const u16* wpk = wpk_all + (size_t)dir * (8 * 64 * 512);

  // load h (bf16 into LDS), c (f32 into regs)
  {
    int srow = tid >> 5, su = (tid & 31) * 8;
    const float* hsrc = hst + ((size_t)(dir * Bx + b0 + srow)) * Hx + su;
#pragma unroll
    for (int j = 0; j < 8; ++j) sh[srow * 264 + su + j] = f2bf(hsrc[j]);
  }
  float creg[2][4];
  int tgt[4];
#pragma unroll
  for (int r = 0; r < 4; ++r) tgt[r] = target[b0 + (l >> 4) * 4 + r];
#pragma unroll
  for (int fc = 0; fc < 2; ++fc) {
    int u = w * 32 + fc * 16 + (l & 15);
#pragma unroll
    for (int r = 0; r < 4; ++r) {
      int row = (l >> 4) * 4 + r;
      creg[fc][r] = cst[((size_t)(dir * Bx + b0 + row)) * Hx + u];
    }
  }

  // prologue: stage kc=0 into buf 0
#pragma unroll
  for (int i = 0; i < 8; ++i)
    gload16((const char*)wpk + i * 8192 + w * 1024 + l * 16,
            (char*)&swb[0][0] + i * 8192 + w * 1024);
  __syncthreads();

  for (int t = 0; t < TCx; ++t) {
    // prefetch xp (gates input-projection + bias), 32 scalar bf16 loads
    float xv[4][2][4];
#pragma unroll
    for (int g = 0; g < 4; ++g)
#pragma unroll
      for (int fc = 0; fc < 2; ++fc) {
        int u = dir * 1024 + g * 256 + w * 32 + fc * 16 + (l & 15);
#pragma unroll
        for (int r = 0; r < 4; ++r) {
          int row = (l >> 4) * 4 + r;
          xv[g][fc][r] = bf2f(xp[((size_t)(b0 + row) * TCx + t) * 2048 + u]);
        }
      }

    f32x4 acc[4][2];
#pragma unroll
    for (int g = 0; g < 4; ++g)
#pragma unroll
      for (int fc = 0; fc < 2; ++fc) acc[g][fc] = f32x4{0.f, 0.f, 0.f, 0.f};

    for (int kc = 0; kc < 8; ++kc) {
      int cur = kc & 1;
      int kcn = (kc + 1) & 7, nb = cur ^ 1;
#pragma unroll
      for (int i = 0; i < 8; ++i)
        gload16((const char*)wpk + kcn * 65536 + i * 8192 + w * 1024 + l * 16,
                (char*)&swb[nb][0] + i * 8192 + w * 1024);
      bf16x8 a = *(const bf16x8*)(sh + (l & 15) * 264 + kc * 32 + ((l >> 4) << 3));
#pragma unroll
      for (int g = 0; g < 4; ++g)
#pragma unroll
        for (int fc = 0; fc < 2; ++fc) {
          int nblk = g * 16 + w * 2 + fc;
          bf16x8 bb = *(const bf16x8*)(&swb[cur][nblk * 512 + l * 8]);
          acc[g][fc] = __builtin_amdgcn_mfma_f32_16x16x32_bf16(a, bb, acc[g][fc], 0, 0, 0);
        }
      __syncthreads();
    }

    // gate nonlinearities + state update (fully in-reg per wave)
    int tg = t0 + t;
#pragma unroll
    for (int fc = 0; fc < 2; ++fc) {
      int u = w * 32 + fc * 16 + (l & 15);
#pragma unroll
      for (int r = 0; r < 4; ++r) {
        int row = (l >> 4) * 4 + r;
        float iv = acc[0][fc][r] + xv[0][fc][r];
        float fv = acc[1][fc][r] + xv[1][fc][r];
        float gv = acc[2][fc][r] + xv[2][fc][r];
        float ov = acc[3][fc][r] + xv[3][fc][r];
        float c = sigf(fv) * creg[fc][r] + sigf(iv) * tanhfast(gv);
        float h = sigf(ov) * tanhfast(c);
        creg[fc][r] = c;
        sh[row * 264 + u] = f2bf(h);
        if (tg == tgt[r]) gath[(size_t)(b0 + row) * 512 + dir * 256 + u] = h;
      }
    }
    __syncthreads();
  }

  // writeback state for next chunk
  {
    int srow = tid >> 5, su = (tid & 31) * 8;
    float* hdst = hst + ((size_t)(dir * Bx + b0 + srow)) * Hx + su;
#pragma unroll
    for (int j = 0; j < 8; ++j) hdst[j] = bf2f(sh[srow * 264 + su + j]);
  }
#pragma unroll
  for (int fc = 0; fc < 2; ++fc) {
    int u = w * 32 + fc * 16 + (l & 15);
#pragma unroll
    for (int r = 0; r < 4; ++r) {
      int row = (l >> 4) * 4 + r;
      cst[((size_t)(dir * Bx + b0 + row)) * Hx + u] = creg[fc][r];
    }
  }
}

// ---------------- output head ----------------
__global__ void k_out(const float* __restrict__ gath, const float* __restrict__ wout,
                      const float* __restrict__ bout, float* __restrict__ out) {
  int b = blockIdx.x, l = threadIdx.x;
  float s = 0.f;
  for (int j = l; j < 512; j += 64) s += gath[(size_t)b * 512 + j] * wout[j];
#pragma unroll
  for (int off = 32; off; off >>= 1) s += __shfl_down(s, off);
  if (l == 0) out[b] = 1.f / (1.f + __expf(-(s + bout[0])));
}

extern "C" void kernel_launch(void* const* d_in, const int* in_sizes, int n_in,
                              void* d_out, int out_size, void* d_ws, size_t ws_size,
                              hipStream_t stream) {
  const int* input = (const int*)d_in[0];
  const int* target = (const int*)d_in[1];
  const float* emb  = (const float*)d_in[3];
  const float* wihf = (const float*)d_in[4];
  const float* whhf = (const float*)d_in[5];
  const float* bihf = (const float*)d_in[6];
  const float* bhhf = (const float*)d_in[7];
  const float* wihb = (const float*)d_in[8];
  const float* whhb = (const float*)d_in[9];
  const float* bihb = (const float*)d_in[10];
  const float* bhhb = (const float*)d_in[11];
  const float* wout = (const float*)d_in[12];
  const float* bout = (const float*)d_in[13];
  float* out = (float*)d_out;

  char* ws = (char*)d_ws;
  u16* embbf  = (u16*)(ws + 0);          // 12,268,032 B
  u16* wih    = (u16*)(ws + 12268032);   //  3,145,728 B  [2048][768] bf16
  u16* wpk    = (u16*)(ws + 15413760);   //  1,048,576 B  packed w_hh
  float* bcat = (float*)(ws + 16462336); //      8,192 B
  float* hst  = (float*)(ws + 16470528); //    524,288 B
  float* cst  = (float*)(ws + 16994816); //    524,288 B
  float* gath = (float*)(ws + 17519104); //    524,288 B
  u16* xp     = (u16*)(ws + 18043392);   // 33,554,432 B  (chunk) -> total ~51.6 MB

  hipMemsetAsync(hst, 0, 524288 * 2, stream);  // zero h and c state
  k_cvt<<<1024, 256, 0, stream>>>(emb, embbf, Vx * Ex);
  k_cvt<<<512, 256, 0, stream>>>(wihf, wih, Gx * Ex);
  k_cvt<<<512, 256, 0, stream>>>(wihb, wih + Gx * Ex, Gx * Ex);
  k_bias<<<4, 256, 0, stream>>>(bihf, bhhf, bihb, bhhb, bcat);
  k_pack_whh<<<512, 256, 0, stream>>>(whhf, whhb, wpk);

  for (int c = 0; c < NCHx; ++c) {
    k_xproj<<<1024, 256, 0, stream>>>(embbf, wih, input, bcat, xp, c * TCx);
    k_rnn<<<32, 512, 0, stream>>>(wpk, xp, target, hst, cst, gath, c * TCx);
  }
  k_out<<<256, 64, 0, stream>>>(gath, wout, bout, out);
}

// Round 2
// 3769.581 us; speedup vs baseline: 1.4697x; 1.4697x over previous
//
#include <hip/hip_runtime.h>
#include <hip/hip_bf16.h>

#define Bx 256
#define Tx 512
#define Ex 768
#define Hx 256
#define Gx 1024
#define Vx 7987
#define TCx 32
#define NCHx 16

typedef unsigned short u16;
typedef unsigned int u32;
typedef __bf16 bf16;
typedef bf16 bf16x8 __attribute__((ext_vector_type(8)));
typedef float f32x4 __attribute__((ext_vector_type(4)));

__device__ __forceinline__ u16 f2bf(float f) {
  union { float f; u32 u; } x; x.f = f;
  u32 r = x.u + 0x7fffu + ((x.u >> 16) & 1u);
  return (u16)(r >> 16);
}
__device__ __forceinline__ float bf2f(u16 b) {
  union { u32 u; float f; } x; x.u = ((u32)b) << 16;
  return x.f;
}
__device__ __forceinline__ void gload16(const void* g, void* l) {
  __builtin_amdgcn_global_load_lds((const __attribute__((address_space(1))) u32*)g,
                                   (__attribute__((address_space(3))) u32*)l, 16, 0, 0);
}
// sigmoid via exp2 + rcp (NaN-free for any finite x)
__device__ __forceinline__ float sigf(float x) {
  return __builtin_amdgcn_rcpf(1.f + __builtin_amdgcn_exp2f(x * -1.442695041f));
}
// raw barrier: drain LDS ops only, leave global loads in flight
__device__ __forceinline__ void bar_ds() {
  __builtin_amdgcn_sched_barrier(0);
  asm volatile("s_waitcnt lgkmcnt(0)" ::: "memory");
  __builtin_amdgcn_s_barrier();
  __builtin_amdgcn_sched_barrier(0);
}

// ---------------- conversion / packing kernels ----------------

__global__ void k_cvt(const float* __restrict__ src, u16* __restrict__ dst, int n) {
  int i = blockIdx.x * blockDim.x + threadIdx.x;
  int st = gridDim.x * blockDim.x;
  for (; i < n; i += st) dst[i] = f2bf(src[i]);
}

__global__ void k_bias(const float* __restrict__ bihf, const float* __restrict__ bhhf,
                       const float* __restrict__ bihb, const float* __restrict__ bhhb,
                       float* __restrict__ bcat) {
  int i = blockIdx.x * blockDim.x + threadIdx.x;
  if (i < Gx) { bcat[i] = bihf[i] + bhhf[i]; bcat[Gx + i] = bihb[i] + bhhb[i]; }
}

// pack w_hh into fragment-linear layout:
// pk[((dir*8 + kc)*64 + nblk)*512 + lane*8 + j] = w[dir][n=nblk*16+(lane&15)][k=kc*32+(lane>>4)*8+j]
__global__ void k_pack_whh(const float* __restrict__ wf, const float* __restrict__ wb,
                           u16* __restrict__ pk) {
  int i = blockIdx.x * blockDim.x + threadIdx.x;
  int st = gridDim.x * blockDim.x;
  for (; i < 2 * 8 * 64 * 512; i += st) {
    int j = i & 7;
    int lane = (i >> 3) & 63;
    int nblk = (i >> 9) & 63;
    int kc = (i >> 15) & 7;
    int dir = i >> 18;
    int n = nblk * 16 + (lane & 15);
    int k = kc * 32 + ((lane >> 4) << 3) + j;
    const float* w = dir ? wb : wf;
    pk[i] = f2bf(w[n * Hx + k]);
  }
}

// ---------------- input projection GEMM (per time-chunk) ----------------
// TRANSPOSED output: xp_t[n][m], m = t_local*256 + b, n = dir*1024 + gate*256 + unit
__global__ __launch_bounds__(256) void k_xproj(
    const u16* __restrict__ embbf, const u16* __restrict__ wih,
    const int* __restrict__ input, const float* __restrict__ bcat,
    u16* __restrict__ xp, int t0) {
  __shared__ u16 sA[128 * 64];
  __shared__ u16 sB[128 * 64];
  const int tid = threadIdx.x;
  const int l = tid & 63, w = tid >> 6;
  const int bx = blockIdx.x & 15, by = blockIdx.x >> 4;
  const int wm = w >> 1, wn = w & 1;
  const int lr = l >> 3, lc = l & 7;

  f32x4 acc[4][4];
#pragma unroll
  for (int a = 0; a < 4; ++a)
#pragma unroll
    for (int b = 0; b < 4; ++b) acc[a][b] = f32x4{0.f, 0.f, 0.f, 0.f};

  // per-lane staging sources (constant across k loop, swizzled within 128B rows)
  size_t asrc[4], bsrc[4];
#pragma unroll
  for (int j = 0; j < 4; ++j) {
    int row = j * 32 + w * 8 + lr;
    int m = by * 128 + row;
    int b = m & 255, tt = m >> 8;           // m = t_local*256 + b
    int er = input[b * Tx + t0 + tt];
    asrc[j] = (size_t)er * (Ex * 2) + (size_t)((lc * 16) ^ ((row & 7) << 4));
    bsrc[j] = (size_t)(bx * 128 + row) * (Ex * 2) + (size_t)((lc * 16) ^ ((row & 7) << 4));
  }

  for (int kt = 0; kt < 12; ++kt) {
    const char* ebase = (const char*)embbf + (size_t)kt * 128;
    const char* wbase = (const char*)wih + (size_t)kt * 128;
#pragma unroll
    for (int j = 0; j < 4; ++j) {
      gload16(ebase + asrc[j], (char*)sA + (j * 32 + w * 8) * 128);
      gload16(wbase + bsrc[j], (char*)sB + (j * 32 + w * 8) * 128);
    }
    __syncthreads();
#pragma unroll
    for (int kk = 0; kk < 2; ++kk) {
      int kb = kk * 64 + ((l >> 4) * 16);
      bf16x8 av[4], bv[4];
#pragma unroll
      for (int f = 0; f < 4; ++f) {
        int r = wm * 64 + f * 16 + (l & 15);
        av[f] = *(const bf16x8*)((const char*)sA + r * 128 + (kb ^ ((r & 7) << 4)));
      }
#pragma unroll
      for (int f = 0; f < 4; ++f) {
        int n = wn * 64 + f * 16 + (l & 15);
        bv[f] = *(const bf16x8*)((const char*)sB + n * 128 + (kb ^ ((n & 7) << 4)));
      }
#pragma unroll
      for (int fm = 0; fm < 4; ++fm)
#pragma unroll
        for (int fn = 0; fn < 4; ++fn)
          acc[fm][fn] = __builtin_amdgcn_mfma_f32_16x16x32_bf16(av[fm], bv[fn], acc[fm][fn], 0, 0, 0);
    }
    __syncthreads();
  }
  // epilogue: add bias, store bf16 TRANSPOSED: xp[col*8192 + m0..m0+3]
#pragma unroll
  for (int fn = 0; fn < 4; ++fn) {
    int col = bx * 128 + wn * 64 + fn * 16 + (l & 15);
    float bias = bcat[col];
#pragma unroll
    for (int fm = 0; fm < 4; ++fm) {
      int m0 = by * 128 + wm * 64 + fm * 16 + ((l >> 4) << 2);
      ushort4 v;
      v.x = f2bf(acc[fm][fn][0] + bias);
      v.y = f2bf(acc[fm][fn][1] + bias);
      v.z = f2bf(acc[fm][fn][2] + bias);
      v.w = f2bf(acc[fm][fn][3] + bias);
      *(ushort4*)(xp + (size_t)col * 8192 + m0) = v;
    }
  }
}

// ---------------- recurrence (per time-chunk) ----------------
// 32 blocks = 2 dirs x 16 batch-slices (16 rows). 8 waves, 512 thr.
// Weights fully resident: kc0-3 in VGPRs, kc4-5 in LDS, kc6-7 time-share one
// 32-reg slot (refilled from L2 with a ~full-step prefetch window).
__global__ __launch_bounds__(512) void k_rnn(
    const u16* __restrict__ wpk_all, const u16* __restrict__ xp,
    const int* __restrict__ target, float* __restrict__ hst,
    float* __restrict__ cst, float* __restrict__ gath, int t0) {
  __shared__ u16 swr[65536];       // 131072 B: kc4,5 fragment-linear
  __shared__ u16 sh[16 * 264];     // h bf16, padded stride
  __shared__ float cl[16 * 260];   // c f32, padded stride

  const int tid = threadIdx.x;
  const int l = tid & 63, w = tid >> 6;
  const int dir = blockIdx.x >> 4, slice = blockIdx.x & 15;
  const int b0 = slice * 16;
  const u16* wpkd = wpk_all + (size_t)dir * 262144;

  // ---- prologue: load resident weights ----
  const u16* wbase = wpkd + (size_t)w * 1024 + (size_t)l * 8;
  bf16x8 wres[4][8];
#pragma unroll
  for (int c = 0; c < 4; ++c)
#pragma unroll
    for (int nt = 0; nt < 8; ++nt)
      wres[c][nt] = *(const bf16x8*)(wbase + c * 32768 + (nt >> 1) * 8192 + (nt & 1) * 512);
  bf16x8 wslot[8];
#pragma unroll
  for (int nt = 0; nt < 8; ++nt)   // slot starts holding kc7
    wslot[nt] = *(const bf16x8*)(wbase + 7 * 32768 + (nt >> 1) * 8192 + (nt & 1) * 512);

  // stage kc4,5 into LDS (131072 B, 16 rounds x 8 KB)
#pragma unroll
  for (int jr = 0; jr < 16; ++jr)
    gload16((const char*)(wpkd + 131072) + jr * 8192 + w * 1024 + l * 16,
            (char*)swr + jr * 8192 + w * 1024);

  // h (bf16) and c (f32) into LDS
  {
    int srow = tid >> 5, su = (tid & 31) * 8;
    const float* hsrc = hst + ((size_t)(dir * Bx + b0 + srow)) * Hx + su;
    const float* csrc = cst + ((size_t)(dir * Bx + b0 + srow)) * Hx + su;
#pragma unroll
    for (int jj = 0; jj < 8; ++jj) {
      sh[srow * 264 + su + jj] = f2bf(hsrc[jj]);
      cl[srow * 260 + su + jj] = csrc[jj];
    }
  }
  int tgt[4];
#pragma unroll
  for (int r = 0; r < 4; ++r) tgt[r] = target[b0 + ((l >> 4) << 2) + r];

  // xp gate-init prefetch (transposed layout), t=0
  const u16* xbb = xp + (size_t)(dir * 1024 + w * 32 + (l & 15)) * 8192 + b0 + ((l >> 4) << 2);
  ushort4 xq[8];
#pragma unroll
  for (int i = 0; i < 8; ++i)
    xq[i] = *(const ushort4*)(xbb + (i >> 1) * 2097152 + (i & 1) * 131072);

  const u16* swb = swr + w * 1024 + l * 8;
  __syncthreads();  // full drain once (covers gload16 staging)

#pragma unroll 1
  for (int t = 0; t < TCx; ++t) {
    // ---- acc init from prefetched xp (x@W_ih + biases) ----
    f32x4 acc[4][2];
#pragma unroll
    for (int g = 0; g < 4; ++g)
#pragma unroll
      for (int fc = 0; fc < 2; ++fc) {
        ushort4 xv = xq[g * 2 + fc];
        acc[g][fc] = f32x4{bf2f(xv.x), bf2f(xv.y), bf2f(xv.z), bf2f(xv.w)};
      }
    // refill xq for t+1 (full-step window)
    if (t + 1 < TCx) {
#pragma unroll
      for (int i = 0; i < 8; ++i)
        xq[i] = *(const ushort4*)(xbb + (i >> 1) * 2097152 + (i & 1) * 131072 + (t + 1) * 256);
    }

    const u16* shr = sh + (l & 15) * 264 + ((l >> 4) << 3);
    // ph kc7 (slot)
    {
      bf16x8 a = *(const bf16x8*)(shr + 7 * 32);
#pragma unroll
      for (int nt = 0; nt < 8; ++nt)
        acc[nt >> 1][nt & 1] = __builtin_amdgcn_mfma_f32_16x16x32_bf16(a, wslot[nt], acc[nt >> 1][nt & 1], 0, 0, 0);
    }
    // refill slot <- kc6 (lands during kc0..5 phases)
#pragma unroll
    for (int nt = 0; nt < 8; ++nt)
      wslot[nt] = *(const bf16x8*)(wbase + 6 * 32768 + (nt >> 1) * 8192 + (nt & 1) * 512);
    // ph kc0..3 (register-resident)
#pragma unroll
    for (int c = 0; c < 4; ++c) {
      bf16x8 a = *(const bf16x8*)(shr + c * 32);
#pragma unroll
      for (int nt = 0; nt < 8; ++nt)
        acc[nt >> 1][nt & 1] = __builtin_amdgcn_mfma_f32_16x16x32_bf16(a, wres[c][nt], acc[nt >> 1][nt & 1], 0, 0, 0);
    }
    // ph kc4,5 (LDS-resident)
#pragma unroll
    for (int c = 0; c < 2; ++c) {
      bf16x8 a = *(const bf16x8*)(shr + (4 + c) * 32);
#pragma unroll
      for (int nt = 0; nt < 8; ++nt) {
        bf16x8 bb = *(const bf16x8*)(swb + c * 32768 + (nt >> 1) * 8192 + (nt & 1) * 512);
        acc[nt >> 1][nt & 1] = __builtin_amdgcn_mfma_f32_16x16x32_bf16(a, bb, acc[nt >> 1][nt & 1], 0, 0, 0);
      }
    }
    // ph kc6 (slot)
    {
      bf16x8 a = *(const bf16x8*)(shr + 6 * 32);
#pragma unroll
      for (int nt = 0; nt < 8; ++nt)
        acc[nt >> 1][nt & 1] = __builtin_amdgcn_mfma_f32_16x16x32_bf16(a, wslot[nt], acc[nt >> 1][nt & 1], 0, 0, 0);
    }
    // refill slot <- kc7 for next step (lands across barrier)
#pragma unroll
    for (int nt = 0; nt < 8; ++nt)
      wslot[nt] = *(const bf16x8*)(wbase + 7 * 32768 + (nt >> 1) * 8192 + (nt & 1) * 512);

    // ---- nonlinearity + state update ----
    float hreg[2][4];
    int tg = t0 + t;
#pragma unroll
    for (int fc = 0; fc < 2; ++fc) {
      int u = w * 32 + fc * 16 + (l & 15);
#pragma unroll
      for (int r = 0; r < 4; ++r) {
        int row = ((l >> 4) << 2) + r;
        float cold = cl[row * 260 + u];
        float sf = sigf(acc[1][fc][r]);
        float si = sigf(acc[0][fc][r]);
        float tg_ = 2.f * sigf(2.f * acc[2][fc][r]) - 1.f;
        float cn = sf * cold + si * tg_;
        float hn = sigf(acc[3][fc][r]) * (2.f * sigf(2.f * cn) - 1.f);
        cl[row * 260 + u] = cn;
        hreg[fc][r] = hn;
        if (tg == tgt[r]) gath[(size_t)(b0 + row) * 512 + dir * 256 + u] = hn;
      }
    }
    bar_ds();  // B1: all sh reads done
#pragma unroll
    for (int fc = 0; fc < 2; ++fc) {
      int u = w * 32 + fc * 16 + (l & 15);
#pragma unroll
      for (int r = 0; r < 4; ++r)
        sh[(((l >> 4) << 2) + r) * 264 + u] = f2bf(hreg[fc][r]);
    }
    bar_ds();  // B2: h writes visible
  }

  // ---- writeback state for next chunk ----
  {
    int srow = tid >> 5, su = (tid & 31) * 8;
    float* hdst = hst + ((size_t)(dir * Bx + b0 + srow)) * Hx + su;
    float* cdst = cst + ((size_t)(dir * Bx + b0 + srow)) * Hx + su;
#pragma unroll
    for (int jj = 0; jj < 8; ++jj) {
      hdst[jj] = bf2f(sh[srow * 264 + su + jj]);
      cdst[jj] = cl[srow * 260 + su + jj];
    }
  }
}

// ---------------- output head ----------------
__global__ void k_out(const float* __restrict__ gath, const float* __restrict__ wout,
                      const float* __restrict__ bout, float* __restrict__ out) {
  int b = blockIdx.x, l = threadIdx.x;
  float s = 0.f;
  for (int j = l; j < 512; j += 64) s += gath[(size_t)b * 512 + j] * wout[j];
#pragma unroll
  for (int off = 32; off; off >>= 1) s += __shfl_down(s, off);
  if (l == 0) out[b] = 1.f / (1.f + __expf(-(s + bout[0])));
}

extern "C" void kernel_launch(void* const* d_in, const int* in_sizes, int n_in,
                              void* d_out, int out_size, void* d_ws, size_t ws_size,
                              hipStream_t stream) {
  const int* input = (const int*)d_in[0];
  const int* target = (const int*)d_in[1];
  const float* emb  = (const float*)d_in[3];
  const float* wihf = (const float*)d_in[4];
  const float* whhf = (const float*)d_in[5];
  const float* bihf = (const float*)d_in[6];
  const float* bhhf = (const float*)d_in[7];
  const float* wihb = (const float*)d_in[8];
  const float* whhb = (const float*)d_in[9];
  const float* bihb = (const float*)d_in[10];
  const float* bhhb = (const float*)d_in[11];
  const float* wout = (const float*)d_in[12];
  const float* bout = (const float*)d_in[13];
  float* out = (float*)d_out;

  char* ws = (char*)d_ws;
  u16* embbf  = (u16*)(ws + 0);          // 12,268,032 B
  u16* wih    = (u16*)(ws + 12268032);   //  3,145,728 B  [2048][768] bf16
  u16* wpk    = (u16*)(ws + 15413760);   //  1,048,576 B  packed w_hh
  float* bcat = (float*)(ws + 16462336); //      8,192 B
  float* hst  = (float*)(ws + 16470528); //    524,288 B
  float* cst  = (float*)(ws + 16994816); //    524,288 B
  float* gath = (float*)(ws + 17519104); //    524,288 B
  u16* xp     = (u16*)(ws + 18043392);   // 33,554,432 B  transposed [2048][8192]

  hipMemsetAsync(hst, 0, 524288 * 2, stream);  // zero h and c state
  k_cvt<<<1024, 256, 0, stream>>>(emb, embbf, Vx * Ex);
  k_cvt<<<512, 256, 0, stream>>>(wihf, wih, Gx * Ex);
  k_cvt<<<512, 256, 0, stream>>>(wihb, wih + Gx * Ex, Gx * Ex);
  k_bias<<<4, 256, 0, stream>>>(bihf, bhhf, bihb, bhhb, bcat);
  k_pack_whh<<<512, 256, 0, stream>>>(whhf, whhb, wpk);

  for (int c = 0; c < NCHx; ++c) {
    k_xproj<<<1024, 256, 0, stream>>>(embbf, wih, input, bcat, xp, c * TCx);
    k_rnn<<<32, 512, 0, stream>>>(wpk, xp, target, hst, cst, gath, c * TCx);
  }
  k_out<<<256, 64, 0, stream>>>(gath, wout, bout, out);
}